// Round 11
// baseline (489.717 us; speedup 1.0000x reference)
//
#include <hip/hip_runtime.h>
#include <hip/hip_bf16.h>

// LGA3D2: out = A_g(A_g(x)); A_g is a 5x5 spatial x 3-depth guided aggregation.
// out[b,c,d,h,w] = sum_{i,j in 5x5, k in 0..2} g[b,(i*5+j)*3+k,h,w] * x[b,c,d+k-1,h+i-2,w+j-2]
// x: [B,C,D,H,W] fp32, g: [B,75,H,W] fp32.
//
// R11 = R10 skeleton (async global_load_lds staging, dbuf across i-taps,
// 4 waves, block=(b,c,dch=16,h), b128-aligned window rows) with the inner
// compute k-SPLIT (gather form): for fixed (i,k) only 5 guidance channels
// are live (~44 live floats total) -> fits the 64-VGPR allocation the
// compiler insists on for this skeleton, eliminating the per-row gr
// reload-from-L2 stalls of R9/R10 (scatter form needed 15 channels = 84
// live). Cost: each slab row is read from LDS 2x more (12 reads/tap/wave
// vs 6) -- LDS pipe has headroom; reload stalls were the limiter.
// Row s = dg*4 + ai + k is always in-slab (zeroed border rows) -> no
// boundary branches in the hot loop.

constexpr int RAD = 2;
constexpr int BB = 2, CC = 16, DD = 48, HH = 128, WW = 256;
constexpr int GG = 75;
constexpr int PLANE = HH * WW;

constexpr int WPT = 4;            // outputs per lane along W
constexpr int DPG = 4;            // depths per wave
constexpr int NWV = 4;            // waves per block
constexpr int DCHUNK = 16;        // depths per block
constexpr int NCH = DD / DCHUNK;  // 3
constexpr int SROWS = DCHUNK + 2; // 18 slab rows (d-1 .. d+16)

using uint = unsigned int;

__device__ __forceinline__ float lo16(uint u) { union {uint i; float f;} c; c.i = u << 16; return c.f; }
__device__ __forceinline__ float hi16(uint u) { union {uint i; float f;} c; c.i = u & 0xFFFF0000u; return c.f; }
__device__ __forceinline__ unsigned short f2bf(float f) {
  union { float f; uint i; } c; c.f = f;
  uint r = c.i + 0x7FFFu + ((c.i >> 16) & 1u);  // round-nearest-even
  return (unsigned short)(r >> 16);
}
__device__ __forceinline__ void store4(float* p, int off, const float* v) {
  float4 t; t.x = v[0]; t.y = v[1]; t.z = v[2]; t.w = v[3];
  *reinterpret_cast<float4*>(p + off) = t;
}
__device__ __forceinline__ void store4(__hip_bfloat16* p, int off, const float* v) {
  ushort4 t; t.x = f2bf(v[0]); t.y = f2bf(v[1]); t.z = f2bf(v[2]); t.w = f2bf(v[3]);
  *reinterpret_cast<ushort4*>(p + off) = t;
}
__device__ __forceinline__ void gload_lds16(const void* gp, void* lp) {
  __builtin_amdgcn_global_load_lds(
      (const __attribute__((address_space(1))) void*)gp,
      (__attribute__((address_space(3))) void*)lp, 16, 0, 0);
}

template <typename IT, typename OT>
__global__ __launch_bounds__(256) void lga_pass(const IT* __restrict__ x,
                                                const float* __restrict__ g,
                                                OT* __restrict__ out) {
  constexpr bool F32 = (sizeof(IT) == 4);
  constexpr int COFF = F32 ? 8 : 4;            // core byte offset (low pad)
  constexpr int ROWB = F32 ? 1040 : 528;       // row bytes (16B multiple)
  __shared__ __align__(16) unsigned char lds[2][SROWS * ROWB];  // 37.4K / 19K

  // XCD-bijective swizzle; logical order: dch fastest, then h, c, b.
  constexpr int NWG = BB * CC * NCH * HH;      // 12288
  const int bx = blockIdx.x;
  const int lid = (bx & 7) * (NWG >> 3) + (bx >> 3);
  const int dch = lid % NCH;
  const int h   = (lid / NCH) % HH;
  const int c   = (lid / (NCH * HH)) % CC;
  const int b   =  lid / (NCH * HH * CC);

  const int tid = threadIdx.x;
  const int lane = tid & 63;
  const int dg = tid >> 6;                     // wave index (uniform)
  const int w0 = lane * WPT;
  const int d0 = dch * DCHUNK + dg * DPG;

  const IT* xb = x + (size_t)(b * CC + c) * DD * PLANE;
  const float* gb = g + (size_t)b * GG * PLANE;
  const int gbase = h * WW + w0;

  // ---- zero init: per-row pads (both bufs); full rows for out-of-range depths
  if (tid < 2 * SROWS) {
    const int buf = tid / SROWS, s = tid % SROWS;
    unsigned char* r = &lds[buf][s * ROWB];
    if constexpr (F32) {
      *reinterpret_cast<uint2*>(r) = make_uint2(0, 0);             // 0..7
      *reinterpret_cast<uint2*>(r + ROWB - 8) = make_uint2(0, 0);  // 1032..1039
    } else {
      *reinterpret_cast<uint*>(r) = 0;                             // 0..3
      *reinterpret_cast<uint*>(r + ROWB - 12) = 0;                 // 516..519
      *reinterpret_cast<uint2*>(r + ROWB - 8) = make_uint2(0, 0);  // 520..527
    }
  }
  constexpr int RDW = ROWB / 4;
  if (dch == 0)
    for (int idx = tid; idx < 2 * RDW; idx += 256)
      reinterpret_cast<uint*>(&lds[idx / RDW][0])[idx % RDW] = 0;
  if (dch == NCH - 1)
    for (int idx = tid; idx < 2 * RDW; idx += 256)
      reinterpret_cast<uint*>(&lds[idx / RDW][(SROWS - 1) * ROWB])[idx % RDW] = 0;

  float acc[DPG][WPT];
#pragma unroll
  for (int a = 0; a < DPG; ++a)
#pragma unroll
    for (int q = 0; q < WPT; ++q) acc[a][q] = 0.f;

  const int ilo = (h >= RAD) ? 0 : RAD - h;
  const int him = HH - 1 + RAD - h;
  const int ihi = (him < 4) ? him : 4;

  // Async-stage one i-slab: wave dg stages rows s = dg, dg+4, ...
  auto stage = [&](int buf, int i) {
    const int hr = h + i - RAD;
#pragma unroll
    for (int t = 0; t < 5; ++t) {
      const int s = dg + NWV * t;
      if (s < SROWS &&
          !(s == 0 && dch == 0) && !(s == SROWS - 1 && dch == NCH - 1)) {
        const int dd = dch * DCHUNK + s - 1;
        const IT* gp = xb + (size_t)dd * PLANE + hr * WW;
        void* lp = &lds[buf][s * ROWB + COFF];   // wave-uniform dest base
        if constexpr (F32) {
          gload_lds16(gp + lane * 4, lp);        // 64 lanes x 16B = 1KB
        } else {
          if (lane < 32) gload_lds16(gp + lane * 8, lp);  // 32 x 16B = 512B
        }
      }
    }
  };

  int cur = 0;
  stage(0, ilo);
  __syncthreads();

  // Per-lane window byte base within a row (start = w0-2):
  //   fp32: COFF + 4*(w0-2) = 16*lane ; bf16: COFF + 2*(w0-2) = 8*lane
  const int wbyte = F32 ? (16 * lane) : (8 * lane);

  for (int ii = ilo; ii <= ihi; ++ii) {
    if (ii < ihi) stage(cur ^ 1, ii + 1);       // async, lands under compute

    const unsigned char* wb = &lds[cur][(dg * DPG) * ROWB] + wbyte;

    // k-split gather: only 5 guidance channels live at a time.
#pragma unroll
    for (int k = 0; k < 3; ++k) {
      float gk[5][WPT];
#pragma unroll
      for (int j = 0; j < 5; ++j) {
        const float4 t4 = *reinterpret_cast<const float4*>(
            gb + (size_t)((ii * 5 + j) * 3 + k) * PLANE + gbase);
        gk[j][0] = t4.x; gk[j][1] = t4.y; gk[j][2] = t4.z; gk[j][3] = t4.w;
      }
#pragma unroll
      for (int ai = 0; ai < DPG; ++ai) {
        // out depth d0+ai reads x depth d0+ai+k-1 -> slab row dg*4 + ai + k
        const unsigned char* rp = wb + (ai + k) * ROWB;  // compile-time offset
        float v[8];                                      // x at w0-2 .. w0+5
        if constexpr (F32) {
          const float4 q0 = *reinterpret_cast<const float4*>(rp);
          const float4 q1 = *reinterpret_cast<const float4*>(rp + 16);
          v[0] = q0.x; v[1] = q0.y; v[2] = q0.z; v[3] = q0.w;
          v[4] = q1.x; v[5] = q1.y; v[6] = q1.z; v[7] = q1.w;
        } else {
          const uint2 q0 = *reinterpret_cast<const uint2*>(rp);
          const uint2 q1 = *reinterpret_cast<const uint2*>(rp + 8);
          v[0] = lo16(q0.x); v[1] = hi16(q0.x); v[2] = lo16(q0.y); v[3] = hi16(q0.y);
          v[4] = lo16(q1.x); v[5] = hi16(q1.x); v[6] = lo16(q1.y); v[7] = hi16(q1.y);
        }
#pragma unroll
        for (int j = 0; j < 5; ++j)
#pragma unroll
          for (int q = 0; q < WPT; ++q)
            acc[ai][q] = fmaf(gk[j][q], v[q + j], acc[ai][q]);
      }
    }
    __syncthreads();   // drains stage(ii+1); buf[cur] reads done before reuse
    cur ^= 1;
  }

  OT* ob = out + (size_t)(b * CC + c) * DD * PLANE;
  const int obase = d0 * PLANE + h * WW + w0;
#pragma unroll
  for (int ai = 0; ai < DPG; ++ai) store4(ob, obase + ai * PLANE, acc[ai]);
}

extern "C" void kernel_launch(void* const* d_in, const int* in_sizes, int n_in,
                              void* d_out, int out_size, void* d_ws, size_t ws_size,
                              hipStream_t stream) {
  const float* x = (const float*)d_in[0];
  const float* g = (const float*)d_in[1];
  float* out = (float*)d_out;

  const size_t elems = (size_t)BB * CC * DD * HH * WW;
  const dim3 grid(BB * CC * NCH * HH);   // 12288
  const dim3 block(64 * NWV);            // 256

  if (ws_size >= elems * sizeof(float)) {
    float* y = (float*)d_ws;
    lga_pass<float, float><<<grid, block, 0, stream>>>(x, g, y);
    lga_pass<float, float><<<grid, block, 0, stream>>>(y, g, out);
  } else {
    __hip_bfloat16* y = (__hip_bfloat16*)d_ws;
    lga_pass<float, __hip_bfloat16><<<grid, block, 0, stream>>>(x, g, y);
    lga_pass<__hip_bfloat16, float><<<grid, block, 0, stream>>>(y, g, out);
  }
}

// Round 12
// 412.527 us; speedup vs baseline: 1.1871x; 1.1871x over previous
//
#include <hip/hip_runtime.h>
#include <hip/hip_bf16.h>

// LGA3D2: out = A_g(A_g(x)); A_g is a 5x5 spatial x 3-depth guided aggregation.
// out[b,c,d,h,w] = sum_{i,j in 5x5, k in 0..2} g[b,(i*5+j)*3+k,h,w] * x[b,c,d+k-1,h+i-2,w+j-2]
// x: [B,C,D,H,W] fp32, g: [B,75,H,W] fp32.
//
// R12: f16 + v_dot2_f32_f16 redesign.
//  - All x/y data in LDS as f16 (rows [4B pad][512B core][12B pad]); pass1
//    reg-stages fp32 x -> pkrtz -> f16 LDS; pass2 reg-stages f16 y directly.
//    Reg-staging (not global_load_lds) escapes the 64-VGPR allocator clamp
//    observed in R9-R11 (R7/R8 reg-staged kernels got 92-104 VGPR).
//  - Guidance packed to f16 PAIRS over j and staged in LDS once per
//    block-tap (9 pair-planes x 256 w): kills the 4x inter-wave redundancy
//    of per-wave g loads (was ~60KB L1 traffic per block-tap -> 15KB) and
//    cuts vmem instrs 15 -> ~4.5 per wave-tap.
//  - Inner loop: v_dot2_f32_f16 consumes f16 pairs straight from LDS
//    (1 op = 2 MACs, zero unpack cvts). Window pairs: 5 even pairs read
//    (2x b64 + 1x b32), 4 odd pairs via v_alignbit.
// LDS: x dbuf 19008 B + g 9216 B = 28224 B -> 5 blocks/CU (20 waves).

constexpr int RAD = 2;
constexpr int BB = 2, CC = 16, DD = 48, HH = 128, WW = 256;
constexpr int GG = 75;
constexpr int PLANE = HH * WW;

constexpr int WPT = 4;            // outputs per lane along W
constexpr int DPG = 4;            // depths per wave
constexpr int NWV = 4;            // waves per block
constexpr int DCHUNK = 16;        // depths per block
constexpr int NCH = DD / DCHUNK;  // 3
constexpr int SROWS = DCHUNK + 2; // 18 slab rows (d-1 .. d+16)
constexpr int ROWB = 528;         // f16 x-slab row bytes: [4][512][12]
constexpr int GPL = 1024;         // g pair-plane bytes (256 x uint)

using uint = unsigned int;
typedef __attribute__((ext_vector_type(2))) _Float16 half2v;

__device__ __forceinline__ uint pkrtz(float a, float b) {
  return __builtin_bit_cast(uint, __builtin_amdgcn_cvt_pkrtz(a, b));
}
__device__ __forceinline__ float fdot2(uint a, uint b, float c) {
#if __has_builtin(__builtin_amdgcn_fdot2)
  return __builtin_amdgcn_fdot2(__builtin_bit_cast(half2v, a),
                                __builtin_bit_cast(half2v, b), c, false);
#else
  half2v av = __builtin_bit_cast(half2v, a), bv = __builtin_bit_cast(half2v, b);
  return c + (float)av.x * (float)bv.x + (float)av.y * (float)bv.y;
#endif
}
__device__ __forceinline__ uint alignp(uint a, uint b) {  // {lo:b.hi, hi:a.lo}
  return __builtin_amdgcn_alignbit(a, b, 16);
}
__device__ __forceinline__ unsigned short f2h(float v) {
  return __builtin_bit_cast(unsigned short, (_Float16)v);
}
__device__ __forceinline__ uint getq(const uint4& v, int q) {
  return q == 0 ? v.x : q == 1 ? v.y : q == 2 ? v.z : v.w;
}

template <typename IT, typename OT>   // IT: float (pass1) | ushort f16 (pass2)
__global__ __launch_bounds__(256) void lga_pass(const IT* __restrict__ x,
                                                const float* __restrict__ g,
                                                OT* __restrict__ out) {
  constexpr bool XF32 = (sizeof(IT) == 4);
  __shared__ __align__(16) unsigned char xs[2][SROWS * ROWB];  // 19008 B
  __shared__ __align__(16) unsigned char gsl[9 * GPL];         // 9216 B

  // XCD-bijective swizzle; dch fastest, then h, c, b.
  constexpr int NWG = BB * CC * NCH * HH;   // 12288
  const int bx = blockIdx.x;
  const int lid = (bx & 7) * (NWG >> 3) + (bx >> 3);
  const int dch = lid % NCH;
  const int h   = (lid / NCH) % HH;
  const int c   = (lid / (NCH * HH)) % CC;
  const int b   =  lid / (NCH * HH * CC);

  const int tid = threadIdx.x;
  const int lane = tid & 63;
  const int dg = tid >> 6;                  // wave index (uniform)
  const int w0 = lane * WPT;
  const int d0 = dch * DCHUNK + dg * DPG;

  const IT* xb = x + (size_t)(b * CC + c) * DD * PLANE;
  const float* gb = g + (size_t)b * GG * PLANE;

  // ---- zero init: per-row pads (both bufs) + out-of-range border depth rows
  if (tid < 2 * SROWS) {
    const int buf = tid / SROWS, s = tid % SROWS;
    unsigned char* r = &xs[buf][s * ROWB];
    *reinterpret_cast<uint*>(r) = 0;                           // w = -2,-1
    *reinterpret_cast<uint*>(r + 516) = 0;                     // w = 256,257
    *reinterpret_cast<uint2*>(r + 520) = make_uint2(0, 0);     // w = 258..261
  }
  constexpr int RDW = ROWB / 4;
  if (dch == 0)
    for (int idx = tid; idx < 2 * RDW; idx += 256)
      reinterpret_cast<uint*>(&xs[idx / RDW][0])[idx % RDW] = 0;
  if (dch == NCH - 1)
    for (int idx = tid; idx < 2 * RDW; idx += 256)
      reinterpret_cast<uint*>(&xs[idx / RDW][(SROWS - 1) * ROWB])[idx % RDW] = 0;

  float acc[DPG][WPT];
#pragma unroll
  for (int a = 0; a < DPG; ++a)
#pragma unroll
    for (int q = 0; q < WPT; ++q) acc[a][q] = 0.f;

  const int ilo = (h >= RAD) ? 0 : RAD - h;
  const int him = HH - 1 + RAD - h;
  const int ihi = (him < 4) ? him : 4;

  uint4 srl[5];   // x stage regs (pass1: 4 floats; pass2: .x/.y = 4 halves)

  auto xstage_load = [&](int i) {
    const int hr = h + i - RAD;
#pragma unroll
    for (int t = 0; t < 5; ++t) {
      const int s = dg + NWV * t;
      if (s < SROWS &&
          !(s == 0 && dch == 0) && !(s == SROWS - 1 && dch == NCH - 1)) {
        const int dd = dch * DCHUNK + s - 1;
        if constexpr (XF32) {
          srl[t] = *reinterpret_cast<const uint4*>(xb + (size_t)dd * PLANE + hr * WW + w0);
        } else {
          const uint2 u = *reinterpret_cast<const uint2*>(xb + (size_t)dd * PLANE + hr * WW + w0);
          srl[t].x = u.x; srl[t].y = u.y;
        }
      }
    }
  };
  auto xstage_write = [&](int buf) {
#pragma unroll
    for (int t = 0; t < 5; ++t) {
      const int s = dg + NWV * t;
      if (s < SROWS &&
          !(s == 0 && dch == 0) && !(s == SROWS - 1 && dch == NCH - 1)) {
        uint lo, hi;
        if constexpr (XF32) {
          lo = pkrtz(__uint_as_float(srl[t].x), __uint_as_float(srl[t].y));
          hi = pkrtz(__uint_as_float(srl[t].z), __uint_as_float(srl[t].w));
        } else {
          lo = srl[t].x; hi = srl[t].y;
        }
        unsigned char* rp = &xs[buf][s * ROWB + 4 + 8 * lane];  // core @ w0
        *reinterpret_cast<uint*>(rp) = lo;
        *reinterpret_cast<uint*>(rp + 4) = hi;
      }
    }
  };

  // g stage: pack f16 j-pairs into 9 LDS planes (p = k*3+jp), once/block-tap.
  // jp0: {g_j0,g_j1}, jp1: {g_j2,g_j3}, jp2: {g_j4, 0}.
  auto gstage = [&](int i) {
#pragma unroll
    for (int r = 0; r < 3; ++r) {
      const int item = tid + (r << 8);
      if (item < 576) {                       // 9 planes x 64 slots
        const int p = item >> 6, slot = item & 63;
        const int k = p / 3, jp = p % 3;
        const int chA = (i * 5 + 2 * jp) * 3 + k;
        const float4 a = *reinterpret_cast<const float4*>(
            gb + (size_t)chA * PLANE + h * WW + 4 * slot);
        float4 bq = make_float4(0.f, 0.f, 0.f, 0.f);
        if (jp < 2)
          bq = *reinterpret_cast<const float4*>(
              gb + (size_t)(chA + 3) * PLANE + h * WW + 4 * slot);
        uint4 u;
        u.x = pkrtz(a.x, bq.x); u.y = pkrtz(a.y, bq.y);
        u.z = pkrtz(a.z, bq.z); u.w = pkrtz(a.w, bq.w);
        *reinterpret_cast<uint4*>(&gsl[p * GPL + 16 * slot]) = u;
      }
    }
  };

  int cur = 0;
  xstage_load(ilo);
  xstage_write(0);
  gstage(ilo);
  __syncthreads();

  for (int ii = ilo; ii <= ihi; ++ii) {
    // G pairs for this tap: plane p, pixels w0..w0+3 (16B/lane).
    uint4 G[9];
#pragma unroll
    for (int p = 0; p < 9; ++p)
      G[p] = *reinterpret_cast<const uint4*>(&gsl[p * GPL + 16 * lane]);

    if (ii < ihi) xstage_load(ii + 1);      // global loads in flight
    __syncthreads();                        // G consumed -> gsl writable
    if (ii < ihi) gstage(ii + 1);           // latency hides under compute

    const unsigned char* wb = &xs[cur][(dg * DPG) * ROWB] + 8 * lane;
#pragma unroll
    for (int a = -1; a <= DPG; ++a) {       // slab rows d0-1 .. d0+4
      const unsigned char* rp = wb + (a + 1) * ROWB;
      // even pairs E[m] = {v2m, v2m+1}; window v0..v9 (v8,v9 pad-safe)
      const uint2 e01 = *reinterpret_cast<const uint2*>(rp);
      const uint2 e23 = *reinterpret_cast<const uint2*>(rp + 8);
      const uint  e4  = *reinterpret_cast<const uint*>(rp + 16);
      uint P[9];
      P[0] = e01.x; P[2] = e01.y; P[4] = e23.x; P[6] = e23.y; P[8] = e4;
      P[1] = alignp(P[2], P[0]);
      P[3] = alignp(P[4], P[2]);
      P[5] = alignp(P[6], P[4]);
      P[7] = alignp(P[8], P[6]);
      // scatter: x row d0+a feeds acc[a+1-k]; per (k,ai,q): 3 dot2
#pragma unroll
      for (int k = 0; k < 3; ++k) {
        const int ai = a + 1 - k;
        if (ai < 0 || ai >= DPG) continue;  // compile-time
#pragma unroll
        for (int q = 0; q < WPT; ++q) {
          float t = acc[ai][q];
          t = fdot2(getq(G[k * 3 + 0], q), P[q], t);
          t = fdot2(getq(G[k * 3 + 1], q), P[q + 2], t);
          t = fdot2(getq(G[k * 3 + 2], q), P[q + 4], t);
          acc[ai][q] = t;
        }
      }
    }
    if (ii < ihi) xstage_write(cur ^ 1);    // vmcnt wait lands after compute
    __syncthreads();                        // xs[nxt] + gsl ready; xs[cur] free
    cur ^= 1;
  }

  const int obase = d0 * PLANE + h * WW + w0;
  if constexpr (sizeof(OT) == 4) {
    float* ob = (float*)out + (size_t)(b * CC + c) * DD * PLANE;
#pragma unroll
    for (int ai = 0; ai < DPG; ++ai) {
      float4 t; t.x = acc[ai][0]; t.y = acc[ai][1]; t.z = acc[ai][2]; t.w = acc[ai][3];
      *reinterpret_cast<float4*>(ob + obase + ai * PLANE) = t;
    }
  } else {
    unsigned short* ob = (unsigned short*)out + (size_t)(b * CC + c) * DD * PLANE;
#pragma unroll
    for (int ai = 0; ai < DPG; ++ai) {
      ushort4 t; t.x = f2h(acc[ai][0]); t.y = f2h(acc[ai][1]);
      t.z = f2h(acc[ai][2]); t.w = f2h(acc[ai][3]);
      *reinterpret_cast<ushort4*>(ob + obase + ai * PLANE) = t;
    }
  }
}

extern "C" void kernel_launch(void* const* d_in, const int* in_sizes, int n_in,
                              void* d_out, int out_size, void* d_ws, size_t ws_size,
                              hipStream_t stream) {
  const float* x = (const float*)d_in[0];
  const float* g = (const float*)d_in[1];
  float* out = (float*)d_out;
  unsigned short* y = (unsigned short*)d_ws;   // f16 intermediate (100 MB)

  const dim3 grid(BB * CC * NCH * HH);   // 12288
  const dim3 block(64 * NWV);            // 256

  lga_pass<float, unsigned short><<<grid, block, 0, stream>>>(x, g, y);
  lga_pass<unsigned short, float><<<grid, block, 0, stream>>>(y, g, out);
}